// Round 13
// baseline (299.062 us; speedup 1.0000x reference)
//
#include <hip/hip_runtime.h>

#define DI __device__ __forceinline__

constexpr int SH_=2, SW_=3;
constexpr int ROWS_=57600;            // B*NW*T*N == B*T*H*W
constexpr float SCALE_=0.17677669529663687f;   // 32^-0.5

typedef unsigned short u16x8 __attribute__((ext_vector_type(8)));
typedef short bf16x8 __attribute__((ext_vector_type(8)));
typedef float f32x4 __attribute__((ext_vector_type(4)));
typedef float f32x16 __attribute__((ext_vector_type(16)));

DI float bf2f(unsigned short u){ return __uint_as_float(((unsigned int)u)<<16); }
DI unsigned short f2bf(float f){
  unsigned int u = __float_as_uint(f);
  u += 0x7fffu + ((u>>16)&1u);          // round to nearest even
  return (unsigned short)(u>>16);
}
// flag f: 1 = external buffers are fp32, 0 = bf16
DI float ldf(const void* p, size_t i, int f){
  return f ? ((const float*)p)[i] : bf2f(((const unsigned short*)p)[i]);
}
DI float4 ldf4(const void* p, size_t i, int f){
  if (f) return *((const float4*)((const float*)p + i));
  ushort4 u = *((const ushort4*)((const unsigned short*)p + i));
  return make_float4(bf2f(u.x),bf2f(u.y),bf2f(u.z),bf2f(u.w));
}

// async global->LDS, 16B per lane. LDS dest = wave-uniform base + lane*16.
DI void gload16(const void* g, void* l){
  __builtin_amdgcn_global_load_lds((const __attribute__((address_space(1))) unsigned int*)g,
                                   (__attribute__((address_space(3))) unsigned int*)l, 16, 0, 0);
}

// XCD-bijective remap (m204)
DI void xcd_remap(int wg, int nb, int nn, int& mt, int& nt){
  const int q = nb>>3, r = nb&7;
  const int x = wg & 7, i = wg >> 3;
  const int base = (x<r) ? x*(q+1) : r*(q+1) + (x-r)*q;
  const int work = base + i;
  mt = work / nn; nt = work - mt*nn;
}

#define WAITV(n) asm volatile("s_waitcnt vmcnt(" #n ")" ::: "memory")

// ---------------- dtype detection: fp32-as-bf16 is detectable ----------------
__global__ void k_detect(const unsigned short* __restrict__ xu, int* __restrict__ flag){
  unsigned short u = xu[threadIdx.x*2];
  int insane = ((u>>7)&0xFF) > 0xC0;
  unsigned long long m = __ballot(insane);
  if (threadIdx.x==0) *flag = m ? 1 : 0;
}

// ---------------- one-time weight convert+transpose to bf16 WT[n][k] ---------
__global__ __launch_bounds__(256) void k_prepw(
    const void* __restrict__ Wq, const void* __restrict__ Wk,
    const void* __restrict__ Wv, const void* __restrict__ Wo,
    const void* __restrict__ W1, const void* __restrict__ W2,
    unsigned short* __restrict__ wt, const int* __restrict__ flagp)
{
  const int f = *flagp;
  const void* src; int kb, total; size_t off;
  switch(blockIdx.y){
    case 0: src=Wq; kb=8;  total=65536;  off=0;      break;
    case 1: src=Wk; kb=8;  total=65536;  off=65536;  break;
    case 2: src=Wv; kb=8;  total=65536;  off=131072; break;
    case 3: src=Wo; kb=8;  total=65536;  off=196608; break;
    case 4: src=W1; kb=8;  total=262144; off=262144; break;   // [256][1024]
    default:src=W2; kb=10; total=262144; off=524288; break;   // [1024][256]
  }
  const int i = blockIdx.x*256 + threadIdx.x;
  if (i >= total) return;
  const int K = 1<<kb, N = total>>kb;
  const int n = i>>kb, k = i&(K-1);
  wt[off + (size_t)n*K + k] = f2bf(ldf(src, (size_t)k*N + n, f));
}

// ---------------- per-(b,t) positional bias via bf16 WT (contiguous k) -------
__global__ __launch_bounds__(256) void k_posqk(const void* __restrict__ ce,
    const unsigned short* __restrict__ wtq, const unsigned short* __restrict__ wtk,
    const void* __restrict__ bq, const void* __restrict__ bk,
    float* __restrict__ posq, float* __restrict__ posk, const int* __restrict__ flagp)
{
  const int f = *flagp;
  const int bt = blockIdx.x, mat = blockIdx.y, co = threadIdx.x;
  __shared__ float ces[256];
  ces[co] = ldf(ce, bt*256+co, f);
  __syncthreads();
  const unsigned short* wr = (mat ? wtk : wtq) + (size_t)co*256;
  float s = ldf(mat ? bk : bq, co, f);
  #pragma unroll
  for (int k0=0;k0<256;k0+=8){
    u16x8 wv = *(const u16x8*)(wr + k0);
    #pragma unroll
    for (int j=0;j<8;++j) s += ces[k0+j]*bf2f(wv[j]);
  }
  (mat ? posk : posq)[bt*256+co] = s;
}

// ---------------- LN1 + cyclic shift + window partition + index tables -------
__global__ __launch_bounds__(256) void k_ln1(const void* __restrict__ x,
    const void* __restrict__ g, const void* __restrict__ be,
    unsigned short* __restrict__ xw, unsigned char* __restrict__ rowbt,
    int* __restrict__ srowtab, const int* __restrict__ flagp)
{
  const int f = *flagp;
  const int lane = threadIdx.x & 63;
  const int wv   = threadIdx.x >> 6;
  const int rs   = blockIdx.x*4 + wv;           // spatial row (b,t,r,c)
  float4 u = ldf4(x, (size_t)rs*256 + lane*4, f);
  float s = u.x+u.y+u.z+u.w;
  #pragma unroll
  for (int o=32;o;o>>=1) s += __shfl_xor(s,o,64);
  const float mean = s*(1.f/256.f);
  float d0=u.x-mean, d1=u.y-mean, d2=u.z-mean, d3=u.w-mean;
  float qv = d0*d0+d1*d1+d2*d2+d3*d3;
  #pragma unroll
  for (int o=32;o;o>>=1) qv += __shfl_xor(qv,o,64);
  const float rstd = rsqrtf(qv*(1.f/256.f)+1e-5f);
  float4 gu = ldf4(g, lane*4, f);
  float4 bu = ldf4(be, lane*4, f);
  ushort4 o;
  o.x = f2bf(d0*rstd*gu.x+bu.x);
  o.y = f2bf(d1*rstd*gu.y+bu.y);
  o.z = f2bf(d2*rstd*gu.z+bu.z);
  o.w = f2bf(d3*rstd*gu.w+bu.w);
  const int c = rs % 60, r = (rs/60)%60, t = (rs/3600)&7, b = rs/28800;
  int r2 = r - SH_; if (r2<0) r2+=60;
  int c2 = c - SW_; if (c2<0) c2+=60;
  const int a=r2/5, ii=r2%5, bb=c2/6, jj=c2%6;
  const int rw = ((b*120 + a*10+bb)*8 + t)*30 + ii*6+jj;
  *reinterpret_cast<ushort4*>(xw + (size_t)rw*256 + lane*4) = o;
  if (lane==0){
    rowbt[rw] = (unsigned char)(b*8+t);
    srowtab[rw] = rs;
  }
}

// ---------------- MFMA 128x128 GEMM core: 8 waves, 3-deep pipeline -----------
// Conflict-free swizzle: swz=(r>>1)&3 on both staged source part and ds_read.
template<int K>
DI void mfma_core128(const unsigned short* __restrict__ A, const unsigned short* __restrict__ WT,
                     const int m0, const int n0, f32x4 acc[4][2], unsigned short* lds)
{
  constexpr int STEPS = K/32;
  const int tid = threadIdx.x, lane = tid&63, wave = tid>>6;
  const int wm = (wave>>2)*64, wn = (wave&3)*32;
  const int fr = lane&15;
  const int kqs = ((lane>>4) ^ ((fr>>1)&3))*8;   // conflict-free swizzle key
  #pragma unroll
  for (int i=0;i<4;++i)
    #pragma unroll
    for (int j=0;j<2;++j) acc[i][j] = (f32x4){0.f,0.f,0.f,0.f};
  const int isB = wave>>2;                  // waves 0-3: A, waves 4-7: B
  const int c0 = (wave&3)*128 + lane;       // chunk id in half [0,512)
  const int c1 = c0 + 64;
  const int r0=c0>>2, p0=((c0&3)^((r0>>1)&3));
  const int r1=c1>>2, p1=((c1&3)^((r1>>1)&3));
  const unsigned short* gb = isB ? (WT + (size_t)n0*K) : (A + (size_t)m0*K);
  const unsigned short* g0 = gb + (size_t)r0*K + p0*8;
  const unsigned short* g1 = gb + (size_t)r1*K + p1*8;
  const int ldso = isB*4096 + (wave&3)*1024;   // shorts
  #define STAGE_(d,k0) do{ \
    unsigned short* bse = lds + (d)*8192 + ldso; \
    gload16(g0+(k0), bse); \
    gload16(g1+(k0), bse+512); }while(0)
  STAGE_(0,0);
  STAGE_(1,32);
  int cur = 0;
  for (int t=0; t<STEPS; ++t){
    if (t+2 < STEPS){
      int nb = cur+2; if (nb>=3) nb-=3;
      STAGE_(nb, (t+2)*32);
      WAITV(4);
    } else if (t+2 == STEPS){
      WAITV(2);
    } else {
      WAITV(0);
    }
    __builtin_amdgcn_s_barrier();
    const unsigned short* At = lds + cur*8192;
    const unsigned short* Bt = At + 4096;
    bf16x8 af[4], bfv[2];
    #pragma unroll
    for (int mi=0;mi<4;++mi) af[mi]  = *(const bf16x8*)(At + (wm+mi*16+fr)*32 + kqs);
    #pragma unroll
    for (int ni=0;ni<2;++ni) bfv[ni] = *(const bf16x8*)(Bt + (wn+ni*16+fr)*32 + kqs);
    __builtin_amdgcn_s_setprio(1);
    #pragma unroll
    for (int mi=0;mi<4;++mi){
      acc[mi][0] = __builtin_amdgcn_mfma_f32_16x16x32_bf16(af[mi], bfv[0], acc[mi][0], 0,0,0);
      acc[mi][1] = __builtin_amdgcn_mfma_f32_16x16x32_bf16(af[mi], bfv[1], acc[mi][1], 0,0,0);
    }
    __builtin_amdgcn_s_setprio(0);
    __builtin_amdgcn_s_barrier();
    cur = (cur+1==3)?0:cur+1;
  }
  #undef STAGE_
}

// ---------------- fused QKV projection (N=768: q|k|v) ------------------------
__global__ __launch_bounds__(512,5) void k_gemm_qkv(const unsigned short* __restrict__ Ain,
    const unsigned short* __restrict__ WT, const float* __restrict__ posq,
    const float* __restrict__ posk, const void* __restrict__ bv,
    unsigned short* __restrict__ qb, unsigned short* __restrict__ kb,
    unsigned short* __restrict__ vb2, const unsigned char* __restrict__ rowbt,
    const int* __restrict__ flagp)
{
  __shared__ __align__(16) unsigned short lds[24576];
  f32x4 acc[4][2];
  int mt, nt; xcd_remap(blockIdx.x, 2700, 6, mt, nt);
  const int m0 = mt*128;
  mfma_core128<256>(Ain, WT, m0, nt*128, acc, lds);
  const int f = *flagp;
  const int tid = threadIdx.x, lane = tid&63, wave = tid>>6;
  const int wm = (wave>>2)*64, wn = (wave&3)*32;
  const int fr = lane&15, fq = lane>>4;
  const int seg = nt>>1;
  unsigned short* ob = seg==0? qb : (seg==1? kb : vb2);
  const float* posb = seg==0? posq : posk;
  // ---- write acc(+bias) -> LDS [128][132] bf16 ----
  #pragma unroll
  for (int mi=0;mi<4;++mi){
    #pragma unroll
    for (int r=0;r<4;++r){
      const int row = wm+mi*16+fq*4+r;
      const int bt2 = rowbt[m0+row];
      #pragma unroll
      for (int ni=0;ni<2;++ni){
        const int lcol = wn+ni*16+fr;
        const int colm = (nt&1)*128 + lcol;
        const float bvv = (seg<2) ? posb[bt2*256+colm] : ldf(bv,colm,f);
        lds[row*132+lcol] = f2bf(acc[mi][ni][r] + bvv);
      }
    }
  }
  __syncthreads();
  // ---- readback wide: 4 threads/row, 4x u16x8 each ----
  const int row = tid>>2;
  unsigned short* dst = ob + (size_t)(m0+row)*256 + (nt&1)*128;
  #pragma unroll
  for (int j=0;j<4;++j){
    const int ci = j*4 + (tid&3);
    *(u16x8*)(dst + ci*8) = *(const u16x8*)(lds + row*132 + ci*8);
  }
}

// ---------------- MFMA attention: one wave per (bt, head) --------------------
__global__ __launch_bounds__(256) void k_attn(const unsigned short* __restrict__ q,
    const unsigned short* __restrict__ k, const unsigned short* __restrict__ v,
    const void* __restrict__ relb, unsigned short* __restrict__ ao,
    const int* __restrict__ flagp)
{
  __shared__ __align__(16) unsigned short vt[4][32*40];   // per-wave V^T [d][m]
  __shared__ __align__(16) unsigned short pa[4][32*40];   // per-wave P [n][m]
  const int f = *flagp;
  const int tid = threadIdx.x, lane = tid&63, wave = tid>>6;
  const int task = blockIdx.x*4 + wave;      // (bt, head)
  const int h = task & 7, bt = task >> 3;
  const int wi = (bt>>3) % 120;
  const int a_ = wi/10, bb_ = wi%10;
  const size_t base = (size_t)bt*7680 + h*32;
  unsigned short* vtw = &vt[wave][0];
  unsigned short* paw = &pa[wave][0];
  if (lane < 60){
    const int m = lane>>1, hf = lane&1;
    const unsigned short* src = v + base + (size_t)m*256 + hf*16;
    u16x8 r0 = *(const u16x8*)(src);
    u16x8 r1 = *(const u16x8*)(src+8);
    #pragma unroll
    for (int j=0;j<8;++j){ vtw[(hf*16+j)*40+m] = r0[j]; vtw[(hf*16+8+j)*40+m] = r1[j]; }
  }
  vtw[(lane>>1)*40 + 30 + (lane&1)] = 0;
  const int n  = lane&31;
  const int hl = lane>>5;
  f32x16 accS = {};
  {
    const unsigned short* ka = k + base + (size_t)n*256 + hl*8;
    const unsigned short* qa = q + base + (size_t)n*256 + hl*8;
    bf16x8 a0 = *(const bf16x8*)(ka);
    bf16x8 b0 = *(const bf16x8*)(qa);
    accS = __builtin_amdgcn_mfma_f32_32x32x16_bf16(a0, b0, accS, 0,0,0);
    bf16x8 a1 = *(const bf16x8*)(ka+16);
    bf16x8 b1 = *(const bf16x8*)(qa+16);
    accS = __builtin_amdgcn_mfma_f32_32x32x16_bf16(a1, b1, accS, 0,0,0);
  }
  const int nc  = (n < 30) ? n : 29;
  const int in_ = nc/6, jn = nc - in_*6;
  const int rn = a_*5+in_, cn = bb_*6+jn;
  const int lnl = (rn<55?0:(rn<58?1:2))*3 + (cn<54?0:(cn<57?1:2));
  #pragma unroll
  for (int r=0;r<16;++r){
    const int m = (r&3) + 8*(r>>2) + 4*hl;
    if (m < 30){
      const int im = m/6, jm = m - im*6;
      const int ridx = (in_-im+4)*11 + (jn-jm+5);
      const float bi = ldf(relb, ridx*8+h, f);
      const int rm = a_*5+im, cm = bb_*6+jm;
      const int lml = (rm<55?0:(rm<58?1:2))*3 + (cm<54?0:(cm<57?1:2));
      accS[r] = accS[r]*SCALE_ + bi + (lnl==lml ? 0.f : -100.f);
    } else accS[r] = -1e30f;
  }
  float mx = accS[0];
  #pragma unroll
  for (int r=1;r<16;++r) mx = fmaxf(mx, accS[r]);
  mx = fmaxf(mx, __shfl_xor(mx, 32, 64));
  float sum = 0.f;
  #pragma unroll
  for (int r=0;r<16;++r){ accS[r] = __expf(accS[r]-mx); sum += accS[r]; }
  sum += __shfl_xor(sum, 32, 64);
  const float inv = 1.f/sum;
  #pragma unroll
  for (int r=0;r<16;++r){
    const int m = (r&3)+8*(r>>2)+4*hl;
    paw[n*40 + m] = f2bf(accS[r]);
  }
  f32x16 accO = {};
  #pragma unroll
  for (int ks=0; ks<2; ++ks){
    bf16x8 av  = *(const bf16x8*)(vtw + n*40 + ks*16 + hl*8);
    bf16x8 pv  = *(const bf16x8*)(paw + n*40 + ks*16 + hl*8);
    accO = __builtin_amdgcn_mfma_f32_32x32x16_bf16(av, pv, accO, 0,0,0);
  }
  if (n < 30){
    #pragma unroll
    for (int g4=0; g4<4; ++g4){
      const int d0 = 8*g4 + 4*hl;
      ushort4 o;
      o.x = f2bf(accO[g4*4+0]*inv);
      o.y = f2bf(accO[g4*4+1]*inv);
      o.z = f2bf(accO[g4*4+2]*inv);
      o.w = f2bf(accO[g4*4+3]*inv);
      *(ushort4*)(ao + base + (size_t)n*256 + d0) = o;
    }
  }
}

// ---------------- Wo projection + window reverse + residual + FUSED LN2 ------
// 128x256 tile (full row) -> epilogue owns complete rows: computes x1 (bf16,
// same double-rounding as the old wo->ln2 chain), writes x1b AND xn2.
// 8 waves x (64x64): 16 MFMA : 8 ds_read per step. 3 gloads/lane/step,
// 3-deep -> WAITV(6/3/0). LDS 3x24KB staging; epilogue [128][264].
__global__ __launch_bounds__(512,4) void k_wo_ln2(const unsigned short* __restrict__ Ain,
    const unsigned short* __restrict__ WT, const void* __restrict__ bias,
    const void* __restrict__ xin, unsigned short* __restrict__ x1b,
    unsigned short* __restrict__ xn2, const void* __restrict__ g2,
    const void* __restrict__ be2, const int* __restrict__ srowtab,
    const int* __restrict__ flagp)
{
  __shared__ __align__(16) unsigned short lds[36864];
  f32x4 acc[4][4];
  int mt, nt; xcd_remap(blockIdx.x, 450, 1, mt, nt);
  const int m0 = mt*128;
  const int tid = threadIdx.x, lane = tid&63, wave = tid>>6;
  const int wm = (wave>>2)*64, wn64 = (wave&3)*64;
  const int fr = lane&15, fq = lane>>4;
  const int kqs = ((lane>>4) ^ ((fr>>1)&3))*8;
  #pragma unroll
  for (int i=0;i<4;++i)
    #pragma unroll
    for (int j=0;j<4;++j) acc[i][j] = (f32x4){0.f,0.f,0.f,0.f};
  // staging: chunk idx=tid -> A row idx>>2 ; B rows idx>>2 and 128+(idx>>2)
  const int rA = tid>>2, pA = (tid&3)^((rA>>1)&3);
  const int rB1 = tid>>2, pB1 = (tid&3)^((rB1>>1)&3);
  const int rB2 = 128 + (tid>>2), pB2 = (tid&3)^((rB2>>1)&3);
  const unsigned short* gA  = Ain + (size_t)(m0+rA)*256 + pA*8;
  const unsigned short* gB1 = WT + (size_t)rB1*256 + pB1*8;
  const unsigned short* gB2 = WT + (size_t)rB2*256 + pB2*8;
  const int wb = wave*512;
  #define STAGEW_(d,k0) do{ \
    unsigned short* bse = lds + (d)*12288; \
    gload16(gA +(k0), bse + wb); \
    gload16(gB1+(k0), bse + 4096 + wb); \
    gload16(gB2+(k0), bse + 8192 + wb); }while(0)
  STAGEW_(0,0);
  STAGEW_(1,32);
  int cur = 0;
  for (int t=0; t<8; ++t){
    if (t+2 < 8){
      int nb = cur+2; if (nb>=3) nb-=3;
      STAGEW_(nb, (t+2)*32);
      WAITV(6);
    } else if (t+2 == 8){
      WAITV(3);
    } else {
      WAITV(0);
    }
    __builtin_amdgcn_s_barrier();
    const unsigned short* At = lds + cur*12288;
    const unsigned short* Bt = At + 4096;
    bf16x8 af[4], bfv[4];
    #pragma unroll
    for (int mi=0;mi<4;++mi) af[mi]  = *(const bf16x8*)(At + (wm+mi*16+fr)*32 + kqs);
    #pragma unroll
    for (int ni=0;ni<4;++ni) bfv[ni] = *(const bf16x8*)(Bt + (wn64+ni*16+fr)*32 + kqs);
    __builtin_amdgcn_s_setprio(1);
    #pragma unroll
    for (int mi=0;mi<4;++mi)
      #pragma unroll
      for (int ni=0;ni<4;++ni)
        acc[mi][ni] = __builtin_amdgcn_mfma_f32_16x16x32_bf16(af[mi], bfv[ni], acc[mi][ni], 0,0,0);
    __builtin_amdgcn_s_setprio(0);
    __builtin_amdgcn_s_barrier();
    cur = (cur+1==3)?0:cur+1;
  }
  #undef STAGEW_
  const int f = *flagp;
  // ---- write acc+bias -> LDS [128][264] bf16 ----
  #pragma unroll
  for (int mi=0;mi<4;++mi){
    #pragma unroll
    for (int ni=0;ni<4;++ni){
      const int col = wn64+ni*16+fr;
      const float bvv = ldf(bias, col, f);
      #pragma unroll
      for (int r=0;r<4;++r){
        const int row = wm+mi*16+fq*4+r;
        lds[row*264+col] = f2bf(acc[mi][ni][r] + bvv);
      }
    }
  }
  __syncthreads();
  // ---- per-row: residual add -> x1b, stats; then LN -> xn2 ----
  const int row = tid>>2;
  const size_t srow = (size_t)srowtab[m0+row];
  const int cb = (tid&3)*8;           // this thread's 8 col-blocks: cb..cb+7
  float s = 0.f, sq = 0.f;
  #pragma unroll
  for (int j=0;j<8;++j){
    const int col = (cb+j)*8;
    u16x8 vv = *(const u16x8*)(lds + row*264 + col);
    float4 xa = ldf4(xin, srow*256+col,   f);
    float4 xb = ldf4(xin, srow*256+col+4, f);
    float xs[8] = {xa.x,xa.y,xa.z,xa.w,xb.x,xb.y,xb.z,xb.w};
    u16x8 o;
    #pragma unroll
    for (int e=0;e<8;++e){
      o[e] = f2bf(bf2f(vv[e]) + xs[e]);
      const float xv = bf2f(o[e]);
      s += xv; sq += xv*xv;
    }
    *(u16x8*)(x1b + srow*256 + col) = o;
    *(u16x8*)(lds + row*264 + col) = o;    // keep x1 bf16 for LN pass
  }
  s  += __shfl_xor(s, 1, 64);  s  += __shfl_xor(s, 2, 64);
  sq += __shfl_xor(sq, 1, 64); sq += __shfl_xor(sq, 2, 64);
  const float mean = s*(1.f/256.f);
  const float var  = sq*(1.f/256.f) - mean*mean;
  const float rstd = rsqrtf(var + 1e-5f);
  #pragma unroll
  for (int j=0;j<8;++j){
    const int col = (cb+j)*8;
    u16x8 vv = *(const u16x8*)(lds + row*264 + col);
    float4 ga = ldf4(g2, col, f), gb = ldf4(g2, col+4, f);
    float4 ba = ldf4(be2, col, f), bb = ldf4(be2, col+4, f);
    float gs[8] = {ga.x,ga.y,ga.z,ga.w,gb.x,gb.y,gb.z,gb.w};
    float bs[8] = {ba.x,ba.y,ba.z,ba.w,bb.x,bb.y,bb.z,bb.w};
    u16x8 o;
    #pragma unroll
    for (int e=0;e<8;++e)
      o[e] = f2bf((bf2f(vv[e])-mean)*rstd*gs[e] + bs[e]);
    *(u16x8*)(xn2 + srow*256 + col) = o;
  }
}

// ---------------- MLP1: xn2 @ W1 + b1 -> exact GELU -> h ---------------------
// NOTE: xn2 is in SPATIAL row order now (LN2 fused into wo writes by srow);
// mlp1/mlp2/out all use the same row space consistently -> unchanged indexing
// works because x1b is also spatial and out rows match x1b rows.
__global__ __launch_bounds__(512,5) void k_mlp1(const unsigned short* __restrict__ Ain,
    const unsigned short* __restrict__ WT, const void* __restrict__ bias,
    unsigned short* __restrict__ hb, const int row0, const int* __restrict__ flagp)
{
  __shared__ __align__(16) unsigned short lds[24576];
  f32x4 acc[4][2];
  int mt, nt; xcd_remap(blockIdx.x, 1800, 8, mt, nt);
  const int m0 = row0 + mt*128, n0 = nt*128;
  mfma_core128<256>(Ain, WT, m0, n0, acc, lds);
  const int f = *flagp;
  const int tid = threadIdx.x, lane = tid&63, wave = tid>>6;
  const int wm = (wave>>2)*64, wn = (wave&3)*32;
  const int fr = lane&15, fq = lane>>4;
  #pragma unroll
  for (int mi=0;mi<4;++mi){
    #pragma unroll
    for (int ni=0;ni<2;++ni){
      const int lcol = wn+ni*16+fr;
      const float bvv = ldf(bias, n0+lcol, f);
      #pragma unroll
      for (int r=0;r<4;++r){
        const int row = wm+mi*16+fq*4+r;
        const float vv = acc[mi][ni][r] + bvv;
        lds[row*132+lcol] = f2bf(0.5f*vv*(1.f+erff(vv*0.70710678118654752f)));
      }
    }
  }
  __syncthreads();
  const int row = tid>>2;
  unsigned short* dst = hb + (size_t)(mt*128+row)*1024 + n0;
  #pragma unroll
  for (int j=0;j<4;++j){
    const int ci = j*4 + (tid&3);
    *(u16x8*)(dst + ci*8) = *(const u16x8*)(lds + row*132 + ci*8);
  }
}

// ---------------- MLP2: h @ W2 + b2 + x1 -> out ------------------------------
__global__ __launch_bounds__(512,5) void k_mlp2(const unsigned short* __restrict__ hbin,
    const unsigned short* __restrict__ WT, const void* __restrict__ bias,
    const unsigned short* __restrict__ x1b, void* __restrict__ outb,
    const int row0, const int* __restrict__ flagp)
{
  __shared__ __align__(16) unsigned short lds[24576];
  f32x4 acc[4][2];
  int mt, nt; xcd_remap(blockIdx.x, 450, 2, mt, nt);
  const int m0l = mt*128, n0 = nt*128;
  mfma_core128<1024>(hbin, WT, m0l, n0, acc, lds);
  const int f = *flagp;
  const int tid = threadIdx.x, lane = tid&63, wave = tid>>6;
  const int wm = (wave>>2)*64, wn = (wave&3)*32;
  const int fr = lane&15, fq = lane>>4;
  #pragma unroll
  for (int mi=0;mi<4;++mi){
    #pragma unroll
    for (int ni=0;ni<2;++ni){
      const int lcol = wn+ni*16+fr;
      const float bvv = ldf(bias, n0+lcol, f);
      #pragma unroll
      for (int r=0;r<4;++r){
        const int row = wm+mi*16+fq*4+r;
        lds[row*132+lcol] = f2bf(acc[mi][ni][r] + bvv);
      }
    }
  }
  __syncthreads();
  const int row = tid>>2;
  const size_t grow = (size_t)(row0 + m0l + row);
  #pragma unroll
  for (int j=0;j<4;++j){
    const int ci = j*4 + (tid&3);
    const int col = n0 + ci*8;
    u16x8 vv = *(const u16x8*)(lds + row*132 + ci*8);
    u16x8 xv = *(const u16x8*)(x1b + grow*256 + col);
    if (f){
      float4 o0, o1;
      o0.x=bf2f(vv[0])+bf2f(xv[0]); o0.y=bf2f(vv[1])+bf2f(xv[1]);
      o0.z=bf2f(vv[2])+bf2f(xv[2]); o0.w=bf2f(vv[3])+bf2f(xv[3]);
      o1.x=bf2f(vv[4])+bf2f(xv[4]); o1.y=bf2f(vv[5])+bf2f(xv[5]);
      o1.z=bf2f(vv[6])+bf2f(xv[6]); o1.w=bf2f(vv[7])+bf2f(xv[7]);
      *(float4*)((float*)outb + grow*256 + col)     = o0;
      *(float4*)((float*)outb + grow*256 + col + 4) = o1;
    } else {
      u16x8 o;
      #pragma unroll
      for (int e=0;e<8;++e) o[e] = f2bf(bf2f(vv[e])+bf2f(xv[e]));
      *(u16x8*)((unsigned short*)outb + grow*256 + col) = o;
    }
  }
}

extern "C" void kernel_launch(void* const* d_in, const int* in_sizes, int n_in,
                              void* d_out, int out_size, void* d_ws, size_t ws_size,
                              hipStream_t stream)
{
  const void* x   = d_in[0];
  const void* ce  = d_in[1];
  const void* g1  = d_in[2];
  const void* be1 = d_in[3];
  const void* Wq  = d_in[4];
  const void* bq  = d_in[5];
  const void* Wk  = d_in[6];
  const void* bk  = d_in[7];
  const void* Wv  = d_in[8];
  const void* bv  = d_in[9];
  const void* rb  = d_in[10];
  const void* Wo  = d_in[11];
  const void* bo  = d_in[12];
  const void* g2  = d_in[13];
  const void* be2 = d_in[14];
  const void* W1  = d_in[15];
  const void* b1  = d_in[16];
  const void* W2  = d_in[17];
  const void* b2  = d_in[18];

  char* ws = (char*)d_ws;
  const size_t SZ = (size_t)ROWS_*256*2;                 // 29,491,200 B
  unsigned short* kbuf = (unsigned short*)(ws);          // [0, SZ)   later: xn2
  unsigned short* vbuf = (unsigned short*)(ws + SZ);     // [SZ, 2SZ)
  unsigned short* xw   = (unsigned short*)(ws + 2*SZ);   // [2SZ,3SZ) later: ao
  unsigned short* qbuf = (unsigned short*)(ws + 3*SZ);   // [3SZ,4SZ) later: x1b
  unsigned short* aob  = xw;
  unsigned short* xn2  = kbuf;                           // q/k dead after attn
  unsigned short* x1b  = qbuf;                           // bf16 x1
  unsigned short* hb   = vbuf;                           // [SZ,3SZ): v+ao dead in MLP
  float* posq = (float*)(ws + 4*SZ);                     // 16KB
  float* posk = posq + 16*256;                           // 16KB
  int*   flag = (int*)(ws + 4*SZ + 32768);
  unsigned short* wt = (unsigned short*)(ws + 4*SZ + 65536);  // 1.5MB bf16 WT
  int*   srowtab = (int*)(ws + 4*SZ + 65536 + 1572864);       // 230KB
  unsigned char* rowbt = (unsigned char*)(ws + 4*SZ + 65536 + 1572864 + 230400); // 57.6KB

  unsigned short* wtqkv = wt;            // q|k|v contiguous: WT[768][256]
  unsigned short* wtq = wt;
  unsigned short* wtk = wt + 65536;
  unsigned short* wto = wt + 196608;
  unsigned short* wt1 = wt + 262144;
  unsigned short* wt2 = wt + 524288;

  k_detect<<<1,64,0,stream>>>((const unsigned short*)x, flag);
  k_prepw<<<dim3(1024,6),256,0,stream>>>(Wq,Wk,Wv,Wo,W1,W2, wt, flag);
  k_posqk<<<dim3(16,2),256,0,stream>>>(ce, wtq, wtk, bq, bk, posq, posk, flag);
  k_ln1<<<14400,256,0,stream>>>(x, g1, be1, xw, rowbt, srowtab, flag);
  k_gemm_qkv<<<2700,512,0,stream>>>(xw, wtqkv, posq, posk, bv, qbuf, kbuf, vbuf, rowbt, flag);
  k_attn<<<3840,256,0,stream>>>(qbuf, kbuf, vbuf, rb, aob, flag);
  k_wo_ln2<<<450,512,0,stream>>>(aob, wto, bo, x, x1b, xn2, g2, be2, srowtab, flag);
  for (int chk=0; chk<2; ++chk){
    const int row0 = chk*28800;
    k_mlp1<<<1800,512,0,stream>>>(xn2, wt1, b1, hb, row0, flag);
    k_mlp2<<<450,512,0,stream>>>(hb, wt2, b2, x1b, d_out, row0, flag);
  }
}

// Round 14
// 272.419 us; speedup vs baseline: 1.0978x; 1.0978x over previous
//
#include <hip/hip_runtime.h>

#define DI __device__ __forceinline__

constexpr int SH_=2, SW_=3;
constexpr int ROWS_=57600;            // B*NW*T*N == B*T*H*W
constexpr float SCALE_=0.17677669529663687f;   // 32^-0.5

typedef unsigned short u16x8 __attribute__((ext_vector_type(8)));
typedef short bf16x8 __attribute__((ext_vector_type(8)));
typedef float f32x4 __attribute__((ext_vector_type(4)));
typedef float f32x16 __attribute__((ext_vector_type(16)));

DI float bf2f(unsigned short u){ return __uint_as_float(((unsigned int)u)<<16); }
DI unsigned short f2bf(float f){
  unsigned int u = __float_as_uint(f);
  u += 0x7fffu + ((u>>16)&1u);          // round to nearest even
  return (unsigned short)(u>>16);
}
// flag f: 1 = external buffers are fp32, 0 = bf16
DI float ldf(const void* p, size_t i, int f){
  return f ? ((const float*)p)[i] : bf2f(((const unsigned short*)p)[i]);
}
DI float4 ldf4(const void* p, size_t i, int f){
  if (f) return *((const float4*)((const float*)p + i));
  ushort4 u = *((const ushort4*)((const unsigned short*)p + i));
  return make_float4(bf2f(u.x),bf2f(u.y),bf2f(u.z),bf2f(u.w));
}

// async global->LDS, 16B per lane. LDS dest = wave-uniform base + lane*16.
DI void gload16(const void* g, void* l){
  __builtin_amdgcn_global_load_lds((const __attribute__((address_space(1))) unsigned int*)g,
                                   (__attribute__((address_space(3))) unsigned int*)l, 16, 0, 0);
}

// XCD-bijective remap (m204)
DI void xcd_remap(int wg, int nb, int nn, int& mt, int& nt){
  const int q = nb>>3, r = nb&7;
  const int x = wg & 7, i = wg >> 3;
  const int base = (x<r) ? x*(q+1) : r*(q+1) + (x-r)*q;
  const int work = base + i;
  mt = work / nn; nt = work - mt*nn;
}

#define WAITV(n) asm volatile("s_waitcnt vmcnt(" #n ")" ::: "memory")

// ---------------- dtype detection: fp32-as-bf16 is detectable ----------------
__global__ void k_detect(const unsigned short* __restrict__ xu, int* __restrict__ flag){
  unsigned short u = xu[threadIdx.x*2];
  int insane = ((u>>7)&0xFF) > 0xC0;
  unsigned long long m = __ballot(insane);
  if (threadIdx.x==0) *flag = m ? 1 : 0;
}

// ---------------- one-time weight convert+transpose to bf16 WT[n][k] ---------
__global__ __launch_bounds__(256) void k_prepw(
    const void* __restrict__ Wq, const void* __restrict__ Wk,
    const void* __restrict__ Wv, const void* __restrict__ Wo,
    const void* __restrict__ W1, const void* __restrict__ W2,
    unsigned short* __restrict__ wt, const int* __restrict__ flagp)
{
  const int f = *flagp;
  const void* src; int kb, total; size_t off;
  switch(blockIdx.y){
    case 0: src=Wq; kb=8;  total=65536;  off=0;      break;
    case 1: src=Wk; kb=8;  total=65536;  off=65536;  break;
    case 2: src=Wv; kb=8;  total=65536;  off=131072; break;
    case 3: src=Wo; kb=8;  total=65536;  off=196608; break;
    case 4: src=W1; kb=8;  total=262144; off=262144; break;   // [256][1024]
    default:src=W2; kb=10; total=262144; off=524288; break;   // [1024][256]
  }
  const int i = blockIdx.x*256 + threadIdx.x;
  if (i >= total) return;
  const int K = 1<<kb, N = total>>kb;
  const int n = i>>kb, k = i&(K-1);
  wt[off + (size_t)n*K + k] = f2bf(ldf(src, (size_t)k*N + n, f));
}

// ---------------- per-(b,t) positional bias via bf16 WT (contiguous k) -------
__global__ __launch_bounds__(256) void k_posqk(const void* __restrict__ ce,
    const unsigned short* __restrict__ wtq, const unsigned short* __restrict__ wtk,
    const void* __restrict__ bq, const void* __restrict__ bk,
    float* __restrict__ posq, float* __restrict__ posk, const int* __restrict__ flagp)
{
  const int f = *flagp;
  const int bt = blockIdx.x, mat = blockIdx.y, co = threadIdx.x;
  __shared__ float ces[256];
  ces[co] = ldf(ce, bt*256+co, f);
  __syncthreads();
  const unsigned short* wr = (mat ? wtk : wtq) + (size_t)co*256;
  float s = ldf(mat ? bk : bq, co, f);
  #pragma unroll
  for (int k0=0;k0<256;k0+=8){
    u16x8 wv = *(const u16x8*)(wr + k0);
    #pragma unroll
    for (int j=0;j<8;++j) s += ces[k0+j]*bf2f(wv[j]);
  }
  (mat ? posk : posq)[bt*256+co] = s;
}

// ---------------- LN1 + cyclic shift + window partition + index tables -------
__global__ __launch_bounds__(256) void k_ln1(const void* __restrict__ x,
    const void* __restrict__ g, const void* __restrict__ be,
    unsigned short* __restrict__ xw, unsigned char* __restrict__ rowbt,
    int* __restrict__ srowtab, const int* __restrict__ flagp)
{
  const int f = *flagp;
  const int lane = threadIdx.x & 63;
  const int wv   = threadIdx.x >> 6;
  const int rs   = blockIdx.x*4 + wv;           // spatial row (b,t,r,c)
  float4 u = ldf4(x, (size_t)rs*256 + lane*4, f);
  float s = u.x+u.y+u.z+u.w;
  #pragma unroll
  for (int o=32;o;o>>=1) s += __shfl_xor(s,o,64);
  const float mean = s*(1.f/256.f);
  float d0=u.x-mean, d1=u.y-mean, d2=u.z-mean, d3=u.w-mean;
  float qv = d0*d0+d1*d1+d2*d2+d3*d3;
  #pragma unroll
  for (int o=32;o;o>>=1) qv += __shfl_xor(qv,o,64);
  const float rstd = rsqrtf(qv*(1.f/256.f)+1e-5f);
  float4 gu = ldf4(g, lane*4, f);
  float4 bu = ldf4(be, lane*4, f);
  ushort4 o;
  o.x = f2bf(d0*rstd*gu.x+bu.x);
  o.y = f2bf(d1*rstd*gu.y+bu.y);
  o.z = f2bf(d2*rstd*gu.z+bu.z);
  o.w = f2bf(d3*rstd*gu.w+bu.w);
  const int c = rs % 60, r = (rs/60)%60, t = (rs/3600)&7, b = rs/28800;
  int r2 = r - SH_; if (r2<0) r2+=60;
  int c2 = c - SW_; if (c2<0) c2+=60;
  const int a=r2/5, ii=r2%5, bb=c2/6, jj=c2%6;
  const int rw = ((b*120 + a*10+bb)*8 + t)*30 + ii*6+jj;
  *reinterpret_cast<ushort4*>(xw + (size_t)rw*256 + lane*4) = o;
  if (lane==0){
    rowbt[rw] = (unsigned char)(b*8+t);
    srowtab[rw] = rs;
  }
}

// ---------------- LN2 (x1b bf16 in ws, bf16 out) ------------------------------
__global__ __launch_bounds__(256) void k_ln2(const unsigned short* __restrict__ x1b,
    const void* __restrict__ g, const void* __restrict__ be,
    unsigned short* __restrict__ xn2, const int* __restrict__ flagp)
{
  const int f = *flagp;
  const int lane = threadIdx.x & 63;
  const int wv   = threadIdx.x >> 6;
  const int rs   = blockIdx.x*4 + wv;
  float4 v = ldf4(x1b, (size_t)rs*256 + lane*4, 0);
  float s = v.x+v.y+v.z+v.w;
  #pragma unroll
  for (int o=32;o;o>>=1) s += __shfl_xor(s,o,64);
  const float mean = s*(1.f/256.f);
  float d0=v.x-mean, d1=v.y-mean, d2=v.z-mean, d3=v.w-mean;
  float qv = d0*d0+d1*d1+d2*d2+d3*d3;
  #pragma unroll
  for (int o=32;o;o>>=1) qv += __shfl_xor(qv,o,64);
  const float rstd = rsqrtf(qv*(1.f/256.f)+1e-5f);
  float4 gu = ldf4(g, lane*4, f);
  float4 bu = ldf4(be, lane*4, f);
  ushort4 o;
  o.x = f2bf(d0*rstd*gu.x+bu.x);
  o.y = f2bf(d1*rstd*gu.y+bu.y);
  o.z = f2bf(d2*rstd*gu.z+bu.z);
  o.w = f2bf(d3*rstd*gu.w+bu.w);
  *reinterpret_cast<ushort4*>(xn2 + (size_t)rs*256 + lane*4) = o;
}

// ---------------- MFMA 128x128 GEMM core: 8 waves, 3-deep pipeline -----------
// Conflict-free swizzle: swz=(r>>1)&3 on both staged source part and ds_read.
template<int K>
DI void mfma_core128(const unsigned short* __restrict__ A, const unsigned short* __restrict__ WT,
                     const int m0, const int n0, f32x4 acc[4][2], unsigned short* lds)
{
  constexpr int STEPS = K/32;
  const int tid = threadIdx.x, lane = tid&63, wave = tid>>6;
  const int wm = (wave>>2)*64, wn = (wave&3)*32;
  const int fr = lane&15;
  const int kqs = ((lane>>4) ^ ((fr>>1)&3))*8;   // conflict-free swizzle key
  #pragma unroll
  for (int i=0;i<4;++i)
    #pragma unroll
    for (int j=0;j<2;++j) acc[i][j] = (f32x4){0.f,0.f,0.f,0.f};
  const int isB = wave>>2;                  // waves 0-3: A, waves 4-7: B
  const int c0 = (wave&3)*128 + lane;       // chunk id in half [0,512)
  const int c1 = c0 + 64;
  const int r0=c0>>2, p0=((c0&3)^((r0>>1)&3));
  const int r1=c1>>2, p1=((c1&3)^((r1>>1)&3));
  const unsigned short* gb = isB ? (WT + (size_t)n0*K) : (A + (size_t)m0*K);
  const unsigned short* g0 = gb + (size_t)r0*K + p0*8;
  const unsigned short* g1 = gb + (size_t)r1*K + p1*8;
  const int ldso = isB*4096 + (wave&3)*1024;   // shorts
  #define STAGE_(d,k0) do{ \
    unsigned short* bse = lds + (d)*8192 + ldso; \
    gload16(g0+(k0), bse); \
    gload16(g1+(k0), bse+512); }while(0)
  STAGE_(0,0);
  STAGE_(1,32);
  int cur = 0;
  for (int t=0; t<STEPS; ++t){
    if (t+2 < STEPS){
      int nb = cur+2; if (nb>=3) nb-=3;
      STAGE_(nb, (t+2)*32);
      WAITV(4);
    } else if (t+2 == STEPS){
      WAITV(2);
    } else {
      WAITV(0);
    }
    __builtin_amdgcn_s_barrier();
    const unsigned short* At = lds + cur*8192;
    const unsigned short* Bt = At + 4096;
    bf16x8 af[4], bfv[2];
    #pragma unroll
    for (int mi=0;mi<4;++mi) af[mi]  = *(const bf16x8*)(At + (wm+mi*16+fr)*32 + kqs);
    #pragma unroll
    for (int ni=0;ni<2;++ni) bfv[ni] = *(const bf16x8*)(Bt + (wn+ni*16+fr)*32 + kqs);
    __builtin_amdgcn_s_setprio(1);
    #pragma unroll
    for (int mi=0;mi<4;++mi){
      acc[mi][0] = __builtin_amdgcn_mfma_f32_16x16x32_bf16(af[mi], bfv[0], acc[mi][0], 0,0,0);
      acc[mi][1] = __builtin_amdgcn_mfma_f32_16x16x32_bf16(af[mi], bfv[1], acc[mi][1], 0,0,0);
    }
    __builtin_amdgcn_s_setprio(0);
    __builtin_amdgcn_s_barrier();
    cur = (cur+1==3)?0:cur+1;
  }
  #undef STAGE_
}

// ---------------- fused QKV projection (N=768: q|k|v) ------------------------
__global__ __launch_bounds__(512,5) void k_gemm_qkv(const unsigned short* __restrict__ Ain,
    const unsigned short* __restrict__ WT, const float* __restrict__ posq,
    const float* __restrict__ posk, const void* __restrict__ bv,
    unsigned short* __restrict__ qb, unsigned short* __restrict__ kb,
    unsigned short* __restrict__ vb2, const unsigned char* __restrict__ rowbt,
    const int* __restrict__ flagp)
{
  __shared__ __align__(16) unsigned short lds[24576];
  f32x4 acc[4][2];
  int mt, nt; xcd_remap(blockIdx.x, 2700, 6, mt, nt);
  const int m0 = mt*128;
  mfma_core128<256>(Ain, WT, m0, nt*128, acc, lds);
  const int f = *flagp;
  const int tid = threadIdx.x, lane = tid&63, wave = tid>>6;
  const int wm = (wave>>2)*64, wn = (wave&3)*32;
  const int fr = lane&15, fq = lane>>4;
  const int seg = nt>>1;
  unsigned short* ob = seg==0? qb : (seg==1? kb : vb2);
  const float* posb = seg==0? posq : posk;
  // ---- write acc(+bias) -> LDS [128][132] bf16 ----
  #pragma unroll
  for (int mi=0;mi<4;++mi){
    #pragma unroll
    for (int r=0;r<4;++r){
      const int row = wm+mi*16+fq*4+r;
      const int bt2 = rowbt[m0+row];
      #pragma unroll
      for (int ni=0;ni<2;++ni){
        const int lcol = wn+ni*16+fr;
        const int colm = (nt&1)*128 + lcol;
        const float bvv = (seg<2) ? posb[bt2*256+colm] : ldf(bv,colm,f);
        lds[row*132+lcol] = f2bf(acc[mi][ni][r] + bvv);
      }
    }
  }
  __syncthreads();
  // ---- readback wide: 4 threads/row, 4x u16x8 each ----
  const int row = tid>>2;
  unsigned short* dst = ob + (size_t)(m0+row)*256 + (nt&1)*128;
  #pragma unroll
  for (int j=0;j<4;++j){
    const int ci = j*4 + (tid&3);
    *(u16x8*)(dst + ci*8) = *(const u16x8*)(lds + row*132 + ci*8);
  }
}

// ---------------- MFMA attention: one wave per (bt, head) --------------------
__global__ __launch_bounds__(256) void k_attn(const unsigned short* __restrict__ q,
    const unsigned short* __restrict__ k, const unsigned short* __restrict__ v,
    const void* __restrict__ relb, unsigned short* __restrict__ ao,
    const int* __restrict__ flagp)
{
  __shared__ __align__(16) unsigned short vt[4][32*40];   // per-wave V^T [d][m]
  __shared__ __align__(16) unsigned short pa[4][32*40];   // per-wave P [n][m]
  const int f = *flagp;
  const int tid = threadIdx.x, lane = tid&63, wave = tid>>6;
  const int task = blockIdx.x*4 + wave;      // (bt, head)
  const int h = task & 7, bt = task >> 3;
  const int wi = (bt>>3) % 120;
  const int a_ = wi/10, bb_ = wi%10;
  const size_t base = (size_t)bt*7680 + h*32;
  unsigned short* vtw = &vt[wave][0];
  unsigned short* paw = &pa[wave][0];
  if (lane < 60){
    const int m = lane>>1, hf = lane&1;
    const unsigned short* src = v + base + (size_t)m*256 + hf*16;
    u16x8 r0 = *(const u16x8*)(src);
    u16x8 r1 = *(const u16x8*)(src+8);
    #pragma unroll
    for (int j=0;j<8;++j){ vtw[(hf*16+j)*40+m] = r0[j]; vtw[(hf*16+8+j)*40+m] = r1[j]; }
  }
  vtw[(lane>>1)*40 + 30 + (lane&1)] = 0;
  const int n  = lane&31;
  const int hl = lane>>5;
  f32x16 accS = {};
  {
    const unsigned short* ka = k + base + (size_t)n*256 + hl*8;
    const unsigned short* qa = q + base + (size_t)n*256 + hl*8;
    bf16x8 a0 = *(const bf16x8*)(ka);
    bf16x8 b0 = *(const bf16x8*)(qa);
    accS = __builtin_amdgcn_mfma_f32_32x32x16_bf16(a0, b0, accS, 0,0,0);
    bf16x8 a1 = *(const bf16x8*)(ka+16);
    bf16x8 b1 = *(const bf16x8*)(qa+16);
    accS = __builtin_amdgcn_mfma_f32_32x32x16_bf16(a1, b1, accS, 0,0,0);
  }
  const int nc  = (n < 30) ? n : 29;
  const int in_ = nc/6, jn = nc - in_*6;
  const int rn = a_*5+in_, cn = bb_*6+jn;
  const int lnl = (rn<55?0:(rn<58?1:2))*3 + (cn<54?0:(cn<57?1:2));
  #pragma unroll
  for (int r=0;r<16;++r){
    const int m = (r&3) + 8*(r>>2) + 4*hl;
    if (m < 30){
      const int im = m/6, jm = m - im*6;
      const int ridx = (in_-im+4)*11 + (jn-jm+5);
      const float bi = ldf(relb, ridx*8+h, f);
      const int rm = a_*5+im, cm = bb_*6+jm;
      const int lml = (rm<55?0:(rm<58?1:2))*3 + (cm<54?0:(cm<57?1:2));
      accS[r] = accS[r]*SCALE_ + bi + (lnl==lml ? 0.f : -100.f);
    } else accS[r] = -1e30f;
  }
  float mx = accS[0];
  #pragma unroll
  for (int r=1;r<16;++r) mx = fmaxf(mx, accS[r]);
  mx = fmaxf(mx, __shfl_xor(mx, 32, 64));
  float sum = 0.f;
  #pragma unroll
  for (int r=0;r<16;++r){ accS[r] = __expf(accS[r]-mx); sum += accS[r]; }
  sum += __shfl_xor(sum, 32, 64);
  const float inv = 1.f/sum;
  #pragma unroll
  for (int r=0;r<16;++r){
    const int m = (r&3)+8*(r>>2)+4*hl;
    paw[n*40 + m] = f2bf(accS[r]);
  }
  f32x16 accO = {};
  #pragma unroll
  for (int ks=0; ks<2; ++ks){
    bf16x8 av  = *(const bf16x8*)(vtw + n*40 + ks*16 + hl*8);
    bf16x8 pv  = *(const bf16x8*)(paw + n*40 + ks*16 + hl*8);
    accO = __builtin_amdgcn_mfma_f32_32x32x16_bf16(av, pv, accO, 0,0,0);
  }
  if (n < 30){
    #pragma unroll
    for (int g4=0; g4<4; ++g4){
      const int d0 = 8*g4 + 4*hl;
      ushort4 o;
      o.x = f2bf(accO[g4*4+0]*inv);
      o.y = f2bf(accO[g4*4+1]*inv);
      o.z = f2bf(accO[g4*4+2]*inv);
      o.w = f2bf(accO[g4*4+3]*inv);
      *(ushort4*)(ao + base + (size_t)n*256 + d0) = o;
    }
  }
}

// ---------------- Wo projection + window reverse + un-shift + residual -------
__global__ __launch_bounds__(512,5) void k_gemm_wo(const unsigned short* __restrict__ Ain,
    const unsigned short* __restrict__ WT, const void* __restrict__ bias,
    const void* __restrict__ xin, unsigned short* __restrict__ x1b,
    const int* __restrict__ srowtab, const int* __restrict__ flagp)
{
  __shared__ __align__(16) unsigned short lds[24576];
  f32x4 acc[4][2];
  int mt, nt; xcd_remap(blockIdx.x, 900, 2, mt, nt);
  const int m0 = mt*128, n0 = nt*128;
  mfma_core128<256>(Ain, WT, m0, n0, acc, lds);
  const int f = *flagp;
  const int tid = threadIdx.x, lane = tid&63, wave = tid>>6;
  const int wm = (wave>>2)*64, wn = (wave&3)*32;
  const int fr = lane&15, fq = lane>>4;
  #pragma unroll
  for (int mi=0;mi<4;++mi){
    #pragma unroll
    for (int ni=0;ni<2;++ni){
      const int lcol = wn+ni*16+fr;
      const float bvv = ldf(bias, n0+lcol, f);
      #pragma unroll
      for (int r=0;r<4;++r){
        const int row = wm+mi*16+fq*4+r;
        lds[row*132+lcol] = f2bf(acc[mi][ni][r] + bvv);
      }
    }
  }
  __syncthreads();
  const int row = tid>>2;
  const size_t srow = (size_t)srowtab[m0+row];
  #pragma unroll
  for (int j=0;j<4;++j){
    const int ci = j*4 + (tid&3);
    const int col = n0 + ci*8;
    u16x8 vv = *(const u16x8*)(lds + row*132 + ci*8);
    float4 xa = ldf4(xin, srow*256+col,   f);
    float4 xbv= ldf4(xin, srow*256+col+4, f);
    u16x8 o;
    o[0]=f2bf(bf2f(vv[0])+xa.x); o[1]=f2bf(bf2f(vv[1])+xa.y);
    o[2]=f2bf(bf2f(vv[2])+xa.z); o[3]=f2bf(bf2f(vv[3])+xa.w);
    o[4]=f2bf(bf2f(vv[4])+xbv.x); o[5]=f2bf(bf2f(vv[5])+xbv.y);
    o[6]=f2bf(bf2f(vv[6])+xbv.z); o[7]=f2bf(bf2f(vv[7])+xbv.w);
    *(u16x8*)(x1b + srow*256 + col) = o;
  }
}

// ---------------- MLP1: xn2 @ W1 + b1 -> exact GELU -> h ---------------------
__global__ __launch_bounds__(512,5) void k_mlp1(const unsigned short* __restrict__ Ain,
    const unsigned short* __restrict__ WT, const void* __restrict__ bias,
    unsigned short* __restrict__ hb, const int row0, const int* __restrict__ flagp)
{
  __shared__ __align__(16) unsigned short lds[24576];
  f32x4 acc[4][2];
  int mt, nt; xcd_remap(blockIdx.x, 1800, 8, mt, nt);
  const int m0 = row0 + mt*128, n0 = nt*128;
  mfma_core128<256>(Ain, WT, m0, n0, acc, lds);
  const int f = *flagp;
  const int tid = threadIdx.x, lane = tid&63, wave = tid>>6;
  const int wm = (wave>>2)*64, wn = (wave&3)*32;
  const int fr = lane&15, fq = lane>>4;
  #pragma unroll
  for (int mi=0;mi<4;++mi){
    #pragma unroll
    for (int ni=0;ni<2;++ni){
      const int lcol = wn+ni*16+fr;
      const float bvv = ldf(bias, n0+lcol, f);
      #pragma unroll
      for (int r=0;r<4;++r){
        const int row = wm+mi*16+fq*4+r;
        const float vv = acc[mi][ni][r] + bvv;
        lds[row*132+lcol] = f2bf(0.5f*vv*(1.f+erff(vv*0.70710678118654752f)));
      }
    }
  }
  __syncthreads();
  const int row = tid>>2;
  unsigned short* dst = hb + (size_t)(mt*128+row)*1024 + n0;
  #pragma unroll
  for (int j=0;j<4;++j){
    const int ci = j*4 + (tid&3);
    *(u16x8*)(dst + ci*8) = *(const u16x8*)(lds + row*132 + ci*8);
  }
}

// ---------------- MLP2: h @ W2 + b2 + x1 -> out ------------------------------
__global__ __launch_bounds__(512,5) void k_mlp2(const unsigned short* __restrict__ hbin,
    const unsigned short* __restrict__ WT, const void* __restrict__ bias,
    const unsigned short* __restrict__ x1b, void* __restrict__ outb,
    const int row0, const int* __restrict__ flagp)
{
  __shared__ __align__(16) unsigned short lds[24576];
  f32x4 acc[4][2];
  int mt, nt; xcd_remap(blockIdx.x, 450, 2, mt, nt);
  const int m0l = mt*128, n0 = nt*128;
  mfma_core128<1024>(hbin, WT, m0l, n0, acc, lds);
  const int f = *flagp;
  const int tid = threadIdx.x, lane = tid&63, wave = tid>>6;
  const int wm = (wave>>2)*64, wn = (wave&3)*32;
  const int fr = lane&15, fq = lane>>4;
  #pragma unroll
  for (int mi=0;mi<4;++mi){
    #pragma unroll
    for (int ni=0;ni<2;++ni){
      const int lcol = wn+ni*16+fr;
      const float bvv = ldf(bias, n0+lcol, f);
      #pragma unroll
      for (int r=0;r<4;++r){
        const int row = wm+mi*16+fq*4+r;
        lds[row*132+lcol] = f2bf(acc[mi][ni][r] + bvv);
      }
    }
  }
  __syncthreads();
  const int row = tid>>2;
  const size_t grow = (size_t)(row0 + m0l + row);
  #pragma unroll
  for (int j=0;j<4;++j){
    const int ci = j*4 + (tid&3);
    const int col = n0 + ci*8;
    u16x8 vv = *(const u16x8*)(lds + row*132 + ci*8);
    u16x8 xv = *(const u16x8*)(x1b + grow*256 + col);
    if (f){
      float4 o0, o1;
      o0.x=bf2f(vv[0])+bf2f(xv[0]); o0.y=bf2f(vv[1])+bf2f(xv[1]);
      o0.z=bf2f(vv[2])+bf2f(xv[2]); o0.w=bf2f(vv[3])+bf2f(xv[3]);
      o1.x=bf2f(vv[4])+bf2f(xv[4]); o1.y=bf2f(vv[5])+bf2f(xv[5]);
      o1.z=bf2f(vv[6])+bf2f(xv[6]); o1.w=bf2f(vv[7])+bf2f(xv[7]);
      *(float4*)((float*)outb + grow*256 + col)     = o0;
      *(float4*)((float*)outb + grow*256 + col + 4) = o1;
    } else {
      u16x8 o;
      #pragma unroll
      for (int e=0;e<8;++e) o[e] = f2bf(bf2f(vv[e])+bf2f(xv[e]));
      *(u16x8*)((unsigned short*)outb + grow*256 + col) = o;
    }
  }
}

extern "C" void kernel_launch(void* const* d_in, const int* in_sizes, int n_in,
                              void* d_out, int out_size, void* d_ws, size_t ws_size,
                              hipStream_t stream)
{
  const void* x   = d_in[0];
  const void* ce  = d_in[1];
  const void* g1  = d_in[2];
  const void* be1 = d_in[3];
  const void* Wq  = d_in[4];
  const void* bq  = d_in[5];
  const void* Wk  = d_in[6];
  const void* bk  = d_in[7];
  const void* Wv  = d_in[8];
  const void* bv  = d_in[9];
  const void* rb  = d_in[10];
  const void* Wo  = d_in[11];
  const void* bo  = d_in[12];
  const void* g2  = d_in[13];
  const void* be2 = d_in[14];
  const void* W1  = d_in[15];
  const void* b1  = d_in[16];
  const void* W2  = d_in[17];
  const void* b2  = d_in[18];

  char* ws = (char*)d_ws;
  const size_t SZ = (size_t)ROWS_*256*2;                 // 29,491,200 B
  unsigned short* kbuf = (unsigned short*)(ws);          // [0, SZ)   later: xn2
  unsigned short* vbuf = (unsigned short*)(ws + SZ);     // [SZ, 2SZ)
  unsigned short* xw   = (unsigned short*)(ws + 2*SZ);   // [2SZ,3SZ) later: ao
  unsigned short* qbuf = (unsigned short*)(ws + 3*SZ);   // [3SZ,4SZ) later: x1b
  unsigned short* aob  = xw;
  unsigned short* xn2  = kbuf;                           // q/k dead after attn
  unsigned short* x1b  = qbuf;                           // bf16 x1
  unsigned short* hb   = vbuf;                           // [SZ,3SZ): v+ao dead in MLP
  float* posq = (float*)(ws + 4*SZ);                     // 16KB
  float* posk = posq + 16*256;                           // 16KB
  int*   flag = (int*)(ws + 4*SZ + 32768);
  unsigned short* wt = (unsigned short*)(ws + 4*SZ + 65536);  // 1.5MB bf16 WT
  int*   srowtab = (int*)(ws + 4*SZ + 65536 + 1572864);       // 230KB
  unsigned char* rowbt = (unsigned char*)(ws + 4*SZ + 65536 + 1572864 + 230400); // 57.6KB

  unsigned short* wtqkv = wt;            // q|k|v contiguous: WT[768][256]
  unsigned short* wtq = wt;
  unsigned short* wtk = wt + 65536;
  unsigned short* wto = wt + 196608;
  unsigned short* wt1 = wt + 262144;
  unsigned short* wt2 = wt + 524288;

  k_detect<<<1,64,0,stream>>>((const unsigned short*)x, flag);
  k_prepw<<<dim3(1024,6),256,0,stream>>>(Wq,Wk,Wv,Wo,W1,W2, wt, flag);
  k_posqk<<<dim3(16,2),256,0,stream>>>(ce, wtq, wtk, bq, bk, posq, posk, flag);
  k_ln1<<<14400,256,0,stream>>>(x, g1, be1, xw, rowbt, srowtab, flag);
  k_gemm_qkv<<<2700,512,0,stream>>>(xw, wtqkv, posq, posk, bv, qbuf, kbuf, vbuf, rowbt, flag);
  k_attn<<<3840,256,0,stream>>>(qbuf, kbuf, vbuf, rb, aob, flag);
  k_gemm_wo<<<900,512,0,stream>>>(aob, wto, bo, x, x1b, srowtab, flag);
  k_ln2<<<14400,256,0,stream>>>(x1b, g2, be2, xn2, flag);
  for (int chk=0; chk<2; ++chk){
    const int row0 = chk*28800;
    k_mlp1<<<1800,512,0,stream>>>(xn2, wt1, b1, hb, row0, flag);
    k_mlp2<<<450,512,0,stream>>>(hb, wt2, b2, x1b, d_out, row0, flag);
  }
}